// Round 12
// baseline (1155.245 us; speedup 1.0000x reference)
//
#include <hip/hip_runtime.h>
#include <hip/hip_bf16.h>

typedef unsigned short u16;
typedef unsigned int u32;
typedef unsigned long long u64;
typedef __attribute__((ext_vector_type(8))) short short8v;
typedef __attribute__((ext_vector_type(4))) float f32x4;

#define SCALE 0.125f

__device__ __forceinline__ float bf2f(u16 u){
    union { u32 i; float f; } c; c.i = ((u32)u) << 16; return c.f;
}
__device__ __forceinline__ u16 f2bf(float f){
    __hip_bfloat16 h = __float2bfloat16(f);
    union { __hip_bfloat16 h; u16 u; } c; c.h = h; return c.u;
}

// ---------------- x = atom_emb[atoms] (fp32 -> bf16) ----------------
__global__ void k_gather(const int* __restrict__ atoms, const float* __restrict__ emb,
                         u16* __restrict__ x, int n){
    int i = blockIdx.x * blockDim.x + threadIdx.x;
    if (i >= n * 16) return;
    int node = i >> 4, f = i & 15;
    int a = atoms[node];
    float4 v = ((const float4*)emb)[a * 16 + f];
    ushort4 o = { f2bf(v.x), f2bf(v.y), f2bf(v.z), f2bf(v.w) };
    ((ushort4*)x)[i] = o;
}

// ---------------- EW[dh][eid][64] = edge_emb[eid] @ We[dh] ----------------
__global__ void k_ew(const float* __restrict__ edge_emb, const float* __restrict__ We,
                     float* __restrict__ EW){
    int t = blockIdx.x * blockDim.x + threadIdx.x;
    if (t >= 2 * 4 * 3 * 64) return;
    int j = t & 63, r = t >> 6;
    int eid = r % 3, dh = r / 3;
    float s = 0.f;
    for (int c = 0; c < 12; ++c)
        s += edge_emb[eid * 12 + c] * We[(dh * 12 + c) * 64 + j];
    EW[(dh * 3 + eid) * 64 + j] = s;
}

// ---------------- CSR build ----------------
__global__ void k_count(const int* __restrict__ ei, u32* cnt_t, u32* cnt_s, int E){
    int e = blockIdx.x * blockDim.x + threadIdx.x;
    if (e >= E) return;
    atomicAdd(&cnt_t[ei[E + e]], 1u);
    atomicAdd(&cnt_s[ei[e]], 1u);
}

// Hierarchical scan: 1024 elems/block (4/thread), ONE packed u64 atomic per block.
__global__ __launch_bounds__(256) void k_scan(
    const u32* __restrict__ cnt_t, const u32* __restrict__ cnt_s,
    u32* __restrict__ start_t, u32* __restrict__ start_s,
    u64* __restrict__ totals, int n)
{
    __shared__ u32 wsum_t[4], wsum_s[4];
    __shared__ u32 base_t, base_s;
    const int t0 = blockIdx.x * 1024 + threadIdx.x * 4;
    u32 ct[4], cs[4];
    #pragma unroll
    for (int j = 0; j < 4; ++j){
        int idx = t0 + j;
        ct[j] = (idx < n) ? cnt_t[idx] : 0u;
        cs[j] = (idx < n) ? cnt_s[idx] : 0u;
    }
    u32 tsum_t = ct[0] + ct[1] + ct[2] + ct[3];
    u32 tsum_s = cs[0] + cs[1] + cs[2] + cs[3];
    const int lane = threadIdx.x & 63, wv = threadIdx.x >> 6;
    u32 it = tsum_t, is = tsum_s;
    for (int d = 1; d < 64; d <<= 1){
        u32 a = __shfl_up(it, d);
        u32 b = __shfl_up(is, d);
        if (lane >= d){ it += a; is += b; }
    }
    if (lane == 63){ wsum_t[wv] = it; wsum_s[wv] = is; }
    __syncthreads();
    if (threadIdx.x == 0){
        u32 a0 = wsum_t[0], a1 = wsum_t[1], a2 = wsum_t[2], a3 = wsum_t[3];
        u32 b0 = wsum_s[0], b1 = wsum_s[1], b2 = wsum_s[2], b3 = wsum_s[3];
        u64 old = atomicAdd(totals, ((u64)(b0 + b1 + b2 + b3) << 32) | (u64)(a0 + a1 + a2 + a3));
        base_t = (u32)(old & 0xFFFFFFFFull);
        base_s = (u32)(old >> 32);
        wsum_t[0] = 0; wsum_t[1] = a0; wsum_t[2] = a0 + a1; wsum_t[3] = a0 + a1 + a2;
        wsum_s[0] = 0; wsum_s[1] = b0; wsum_s[2] = b0 + b1; wsum_s[3] = b0 + b1 + b2;
    }
    __syncthreads();
    u32 ex_t = base_t + wsum_t[wv] + (it - tsum_t);
    u32 ex_s = base_s + wsum_s[wv] + (is - tsum_s);
    #pragma unroll
    for (int j = 0; j < 4; ++j){
        int idx = t0 + j;
        if (idx < n){
            start_t[idx] = ex_t; start_s[idx] = ex_s;
            ex_t += ct[j]; ex_s += cs[j];
        }
    }
}

__global__ void k_fill(const int* __restrict__ ei, const int* __restrict__ eids,
                       const u32* __restrict__ start_t, const u32* __restrict__ start_s,
                       u32* cur_t, u32* cur_s, int* adj_t, int* adj_s, int E){
    int e = blockIdx.x * blockDim.x + threadIdx.x;
    if (e >= E) return;
    int s = ei[e], t = ei[E + e], id = eids[e];
    u32 p = atomicAdd(&cur_t[t], 1u);
    adj_t[start_t[t] + p] = s | (id << 20);
    u32 p2 = atomicAdd(&cur_s[s], 1u);
    adj_s[start_s[s] + p2] = t | (id << 20);
}

// ---------------- node GEMM via MFMA: q,k,v = x @ {Wq,Wk,Wv} + b (skip moved to aggr) ----
__global__ __launch_bounds__(256) void k_gemm3(
    const u16* __restrict__ x,
    const float* __restrict__ Wq, const float* __restrict__ bq,
    const float* __restrict__ Wk, const float* __restrict__ bk,
    const float* __restrict__ Wv, const float* __restrict__ bv,
    int dh,
    u16* __restrict__ q, u16* __restrict__ k, u16* __restrict__ v, int n)
{
    __shared__ __align__(16) u16 Wt[3][64][64];   // [mat][n][k] bf16, swizzled, 24 KB
    __shared__ __align__(16) u16 Xh[64][64];      // x tile, swizzled, 8 KB
    const int tid = threadIdx.x;
    const int row0 = blockIdx.x * 64;

    const float* wsrc[3] = { Wq + dh * 4096, Wk + dh * 4096, Wv + dh * 4096 };
    for (int m = 0; m < 3; ++m){
        for (int i = tid; i < 1024; i += 256){    // 64 k-rows x 16 float4
            int kk = i >> 4, n4 = (i & 15) * 4;
            float4 w = ((const float4*)(wsrc[m] + (size_t)kk * 64))[i & 15];
            float wf[4] = { w.x, w.y, w.z, w.w };
            #pragma unroll
            for (int c = 0; c < 4; ++c){
                int nn = n4 + c;
                int ps = (kk >> 3) ^ (nn & 7);
                Wt[m][nn][ps * 8 + (kk & 7)] = f2bf(wf[c]);
            }
        }
    }
    for (int i = tid; i < 512; i += 256){         // 64 rows x 8 slots (16B each)
        int r = i >> 3, f = i & 7;
        int gr = row0 + r;
        short8v val = {0,0,0,0,0,0,0,0};
        if (gr < n) val = *(const short8v*)&x[(size_t)gr * 64 + f * 8];
        int ps = f ^ (r & 7);
        *(short8v*)&Xh[r][ps * 8] = val;
    }
    __syncthreads();

    const int wv = tid >> 6, l = tid & 63;
    const int lr = l & 15, lk = l >> 4;
    short8v ah[2];
    #pragma unroll
    for (int ks = 0; ks < 2; ++ks){
        int r = wv * 16 + lr;
        int ps = (lk + 4 * ks) ^ (r & 7);
        ah[ks] = *(const short8v*)&Xh[r][ps * 8];
    }
    const float* bsrc[3] = { bq + dh * 64, bk + dh * 64, bv + dh * 64 };
    u16* outs[3] = { q, k, v };
    for (int m = 0; m < 3; ++m){
        #pragma unroll
        for (int ct = 0; ct < 4; ++ct){
            int col = ct * 16 + lr;
            int s0 = (lk + 0) ^ (col & 7);
            int s1 = (lk + 4) ^ (col & 7);
            short8v b0 = *(const short8v*)&Wt[m][col][s0 * 8];
            short8v b1 = *(const short8v*)&Wt[m][col][s1 * 8];
            float bb = bsrc[m][col];
            f32x4 acc = { bb, bb, bb, bb };
            acc = __builtin_amdgcn_mfma_f32_16x16x32_bf16(ah[0], b0, acc, 0, 0, 0);
            acc = __builtin_amdgcn_mfma_f32_16x16x32_bf16(ah[1], b1, acc, 0, 0, 0);
            int grb = row0 + wv * 16 + lk * 4;    // D: row=(l>>4)*4+j, col=l&15
            u16* o = outs[m];
            #pragma unroll
            for (int j = 0; j < 4; ++j)
                if (grb + j < n) o[(size_t)(grb + j) * 64 + col] = f2bf(acc[j]);
        }
    }
}

// ---------------- node-parallel attention (16 lanes/node), WRITE-ONLY output ----------------
__global__ __launch_bounds__(256) void k_attn(
    const u16* __restrict__ q, const u16* __restrict__ k, const u16* __restrict__ v,
    const int* __restrict__ adj, const u32* __restrict__ start, const u32* __restrict__ cnt,
    const float* __restrict__ EW, u16* __restrict__ outd, int n)
{
    int tid = blockIdx.x * blockDim.x + threadIdx.x;
    int node = tid >> 4;
    int l = tid & 15;
    if (node >= n) return;
    int st = (int)start[node];
    int c  = (int)cnt[node];
    ushort4 qu = ((const ushort4*)q)[node * 16 + l];
    float qx = bf2f(qu.x), qy = bf2f(qu.y), qz = bf2f(qu.z), qw = bf2f(qu.w);
    float4 acc = {0.f, 0.f, 0.f, 0.f};
    float s = 0.f;
    for (int i = 0; i < c; ++i){
        int a = adj[st + i];
        int srcn = a & 0xFFFFF;
        int eid  = ((u32)a) >> 20;
        float4 ew = ((const float4*)EW)[eid * 16 + l];
        ushort4 ku = ((const ushort4*)k)[srcn * 16 + l];
        float kx = bf2f(ku.x) + ew.x, ky = bf2f(ku.y) + ew.y;
        float kz = bf2f(ku.z) + ew.z, kw = bf2f(ku.w) + ew.w;
        float d = qx * kx + qy * ky + qz * kz + qw * kw;
        d += __shfl_xor(d, 1); d += __shfl_xor(d, 2);
        d += __shfl_xor(d, 4); d += __shfl_xor(d, 8);
        float ex = expf(d * SCALE);
        ushort4 vu = ((const ushort4*)v)[srcn * 16 + l];
        acc.x += ex * (bf2f(vu.x) + ew.x);
        acc.y += ex * (bf2f(vu.y) + ew.y);
        acc.z += ex * (bf2f(vu.z) + ew.z);
        acc.w += ex * (bf2f(vu.w) + ew.w);
        s += ex;
    }
    float inv = 1.0f / (s + 1e-16f);
    ushort4 no = { f2bf(acc.x * inv), f2bf(acc.y * inv),
                   f2bf(acc.z * inv), f2bf(acc.w * inv) };
    ((ushort4*)outd)[node * 16 + l] = no;
}

// ---------------- fused aggr: skip = x@Ws+bs (both dirs) computed here via MFMA,
// h = concat(a0+skip0, a1+skip1) @ A + b, x' = gelu(h). LDS aliased: 40 KB total.
__global__ __launch_bounds__(256) void k_aggr(
    const u16* __restrict__ a0, const u16* __restrict__ a1, const u16* __restrict__ xin,
    const float* __restrict__ Ws, const float* __restrict__ bs, int hop,
    const float* __restrict__ A, const float* __restrict__ b,
    u16* __restrict__ xout, float* __restrict__ out_f, int write_out, int n)
{
    __shared__ __align__(16) u16 lds[20480];            // 40 KB
    u16 (*Wt)[128] = (u16(*)[128])lds;                  // [64][128] A^T, swizzled, 16 KB
    u16 (*Xt)[64]  = (u16(*)[64])(lds + 8192);          // [64][64] x tile, 8 KB
    u16 (*Wst0)[64]= (u16(*)[64])(lds + 8192 + 4096);   // Ws^T dir0, 8 KB
    u16 (*Wst1)[64]= (u16(*)[64])(lds + 8192 + 8192);   // Ws^T dir1, 8 KB
    u16 (*Ah)[128] = (u16(*)[128])(lds + 8192);         // phase-3 alias over Xt/Ws*, 16 KB
    const int tid = threadIdx.x;
    const int row0 = blockIdx.x * 64;

    // ---- stage A^T: A[k][n] (128x64) -> Wt[n][k], swizzled ----
    for (int i = tid; i < 2048; i += 256){
        int kk = i >> 4, n4 = (i & 15) * 4;
        float4 w = ((const float4*)(A + (size_t)kk * 64))[i & 15];
        float wf[4] = { w.x, w.y, w.z, w.w };
        #pragma unroll
        for (int c = 0; c < 4; ++c){
            int nn = n4 + c;
            int ps = (kk >> 3) ^ (nn & 7);
            Wt[nn][ps * 8 + (kk & 7)] = f2bf(wf[c]);
        }
    }
    // ---- stage x tile ----
    for (int i = tid; i < 512; i += 256){
        int r = i >> 3, f = i & 7;
        int gr = row0 + r;
        short8v val = {0,0,0,0,0,0,0,0};
        if (gr < n) val = *(const short8v*)&xin[(size_t)gr * 64 + f * 8];
        int ps = f ^ (r & 7);
        *(short8v*)&Xt[r][ps * 8] = val;
    }
    // ---- stage Ws^T both dirs ----
    const float* ws0 = Ws + (size_t)hop * 4096;
    const float* ws1 = Ws + (size_t)(4 + hop) * 4096;
    for (int i = tid; i < 1024; i += 256){
        int kk = i >> 4, n4 = (i & 15) * 4;
        float4 w0 = ((const float4*)(ws0 + (size_t)kk * 64))[i & 15];
        float4 w1 = ((const float4*)(ws1 + (size_t)kk * 64))[i & 15];
        float f0[4] = { w0.x, w0.y, w0.z, w0.w };
        float f1[4] = { w1.x, w1.y, w1.z, w1.w };
        #pragma unroll
        for (int c = 0; c < 4; ++c){
            int nn = n4 + c;
            int ps = (kk >> 3) ^ (nn & 7);
            Wst0[nn][ps * 8 + (kk & 7)] = f2bf(f0[c]);
            Wst1[nn][ps * 8 + (kk & 7)] = f2bf(f1[c]);
        }
    }
    __syncthreads();

    const int wv = tid >> 6, l = tid & 63;
    const int lr = l & 15, lk = l >> 4;
    // ---- phase 2: skip GEMM (both dirs) + add attn result ----
    short8v xf[2];
    #pragma unroll
    for (int ks = 0; ks < 2; ++ks){
        int r = wv * 16 + lr;
        int ps = (lk + 4 * ks) ^ (r & 7);
        xf[ks] = *(const short8v*)&Xt[r][ps * 8];
    }
    f32x4 S[2][4];
    const u16* asrc[2] = { a0, a1 };
    const int grb = row0 + wv * 16 + lk * 4;
    #pragma unroll
    for (int d = 0; d < 2; ++d){
        const float* bsd = bs + (size_t)(d * 4 + hop) * 64;
        u16 (*Wst)[64] = d ? Wst1 : Wst0;
        #pragma unroll
        for (int ct = 0; ct < 4; ++ct){
            int col = ct * 16 + lr;
            int s0 = (lk + 0) ^ (col & 7);
            int s1 = (lk + 4) ^ (col & 7);
            short8v b0 = *(const short8v*)&Wst[col][s0 * 8];
            short8v b1 = *(const short8v*)&Wst[col][s1 * 8];
            float bb = bsd[col];
            f32x4 acc = { bb, bb, bb, bb };
            acc = __builtin_amdgcn_mfma_f32_16x16x32_bf16(xf[0], b0, acc, 0, 0, 0);
            acc = __builtin_amdgcn_mfma_f32_16x16x32_bf16(xf[1], b1, acc, 0, 0, 0);
            #pragma unroll
            for (int j = 0; j < 4; ++j)
                if (grb + j < n) acc[j] += bf2f(asrc[d][(size_t)(grb + j) * 64 + col]);
            S[d][ct] = acc;
        }
    }
    __syncthreads();   // everyone done reading Xt/Ws* before Ah overwrites them
    // ---- phase 3: write concat rows into Ah (swizzled) ----
    #pragma unroll
    for (int d = 0; d < 2; ++d){
        #pragma unroll
        for (int ct = 0; ct < 4; ++ct){
            int col = ct * 16 + lr;
            int kk = d * 64 + col;
            #pragma unroll
            for (int j = 0; j < 4; ++j){
                int r = wv * 16 + lk * 4 + j;
                int ps = (kk >> 3) ^ (r & 7);
                Ah[r][ps * 8 + (kk & 7)] = f2bf(S[d][ct][j]);
            }
        }
    }
    __syncthreads();
    // ---- phase 4: h = Ah @ A + b, gelu, store ----
    short8v ah[4];
    #pragma unroll
    for (int ks = 0; ks < 4; ++ks){
        int r = wv * 16 + lr;
        int ps = (lk + 4 * ks) ^ (r & 7);
        ah[ks] = *(const short8v*)&Ah[r][ps * 8];
    }
    #pragma unroll
    for (int ct = 0; ct < 4; ++ct){
        int col = ct * 16 + lr;
        float bb = b[col];
        f32x4 acc = { bb, bb, bb, bb };
        #pragma unroll
        for (int ks = 0; ks < 4; ++ks){
            int ps = (lk + 4 * ks) ^ (col & 7);
            short8v bf = *(const short8v*)&Wt[col][ps * 8];
            acc = __builtin_amdgcn_mfma_f32_16x16x32_bf16(ah[ks], bf, acc, 0, 0, 0);
        }
        #pragma unroll
        for (int j = 0; j < 4; ++j){
            if (grb + j >= n) continue;
            float h = acc[j];
            float g = 0.5f * h * (1.0f + erff(h * 0.70710678118654752f));
            xout[(size_t)(grb + j) * 64 + col] = f2bf(g);
            if (write_out) out_f[(size_t)(grb + j) * 64 + col] = g;
        }
    }
}

extern "C" void kernel_launch(void* const* d_in, const int* in_sizes, int n_in,
                              void* d_out, int out_size, void* d_ws, size_t ws_size,
                              hipStream_t stream)
{
    const int* atoms      = (const int*)d_in[0];
    const int* ei         = (const int*)d_in[1];
    const int* eids       = (const int*)d_in[2];
    const float* atom_emb = (const float*)d_in[3];
    const float* edge_emb = (const float*)d_in[4];
    const float* Wq = (const float*)d_in[5];  const float* bq = (const float*)d_in[6];
    const float* Wk = (const float*)d_in[7];  const float* bk = (const float*)d_in[8];
    const float* Wv = (const float*)d_in[9];  const float* bv = (const float*)d_in[10];
    const float* We = (const float*)d_in[11];
    const float* Ws = (const float*)d_in[12]; const float* bs = (const float*)d_in[13];
    const float* aggr_W = (const float*)d_in[14];
    const float* aggr_b = (const float*)d_in[15];

    const int N = in_sizes[0];
    const int E = in_sizes[1] / 2;

    char* p = (char*)d_ws;
    auto alloc = [&](size_t bytes){
        void* r = (void*)p;
        p += (bytes + 255) & ~(size_t)255;
        return r;
    };
    u16*   x   = (u16*)  alloc((size_t)N * 64 * 2);
    u16*   qb  = (u16*)  alloc((size_t)N * 64 * 2);
    u16*   kb  = (u16*)  alloc((size_t)N * 64 * 2);
    u16*   vb  = (u16*)  alloc((size_t)N * 64 * 2);
    u16*   o0  = (u16*)  alloc((size_t)N * 64 * 2);
    u16*   o1  = (u16*)  alloc((size_t)N * 64 * 2);
    float* EWt = (float*)alloc(2 * 4 * 3 * 64 * 4);
    int* adj_t = (int*)alloc((size_t)E * 4);
    int* adj_s = (int*)alloc((size_t)E * 4);
    u32* start_t = (u32*)alloc((size_t)N * 4);
    u32* start_s = (u32*)alloc((size_t)N * 4);
    u32* zb = (u32*)alloc(((size_t)4 * N + 2) * 4);   // cnt_t cnt_s cur_t cur_s totals(u64)
    u32* cnt_t = zb;
    u32* cnt_s = zb + N;
    u32* cur_t = zb + 2 * (size_t)N;
    u32* cur_s = zb + 3 * (size_t)N;
    u64* totals = (u64*)(zb + 4 * (size_t)N);   // 4N u32s = 8-byte aligned

    hipMemsetAsync(zb, 0, ((size_t)4 * N + 2) * 4, stream);

    k_gather<<<(N * 16 + 255) / 256, 256, 0, stream>>>(atoms, atom_emb, x, N);
    k_ew<<<6, 256, 0, stream>>>(edge_emb, We, EWt);
    k_count<<<(E + 255) / 256, 256, 0, stream>>>(ei, cnt_t, cnt_s, E);
    k_scan<<<(N + 1023) / 1024, 256, 0, stream>>>(cnt_t, cnt_s, start_t, start_s, totals, N);
    k_fill<<<(E + 255) / 256, 256, 0, stream>>>(ei, eids, start_t, start_s, cur_t, cur_s, adj_t, adj_s, E);

    const int gB = (N + 63) / 64;
    const int gA = (N * 16 + 255) / 256;
    for (int hop = 0; hop < 4; ++hop){
        int dh0 = hop;         // dir 0 (r2c)
        int dh1 = 4 + hop;     // dir 1 (c2r)
        k_gemm3<<<gB, 256, 0, stream>>>(x, Wq, bq, Wk, bk, Wv, bv, dh0, qb, kb, vb, N);
        k_attn<<<gA, 256, 0, stream>>>(qb, kb, vb, adj_t, start_t, cnt_t, EWt + dh0 * 192, o0, N);
        k_gemm3<<<gB, 256, 0, stream>>>(x, Wq, bq, Wk, bk, Wv, bv, dh1, qb, kb, vb, N);
        k_attn<<<gA, 256, 0, stream>>>(qb, kb, vb, adj_s, start_s, cnt_s, EWt + dh1 * 192, o1, N);
        k_aggr<<<gB, 256, 0, stream>>>(o0, o1, x, Ws, bs, hop, aggr_W, aggr_b,
                                       x, (float*)d_out, hop == 3 ? 1 : 0, N);
    }
}

// Round 16
// 1150.452 us; speedup vs baseline: 1.0042x; 1.0042x over previous
//
#include <hip/hip_runtime.h>
#include <hip/hip_bf16.h>

typedef unsigned short u16;
typedef unsigned int u32;
typedef unsigned long long u64;
typedef __attribute__((ext_vector_type(8))) short short8v;
typedef __attribute__((ext_vector_type(4))) float f32x4;

#define SCALE 0.125f

__device__ __forceinline__ float bf2f(u16 u){
    union { u32 i; float f; } c; c.i = ((u32)u) << 16; return c.f;
}
__device__ __forceinline__ u16 f2bf(float f){
    __hip_bfloat16 h = __float2bfloat16(f);
    union { __hip_bfloat16 h; u16 u; } c; c.h = h; return c.u;
}

// ---------------- x = atom_emb[atoms] (fp32 -> bf16) ----------------
__global__ void k_gather(const int* __restrict__ atoms, const float* __restrict__ emb,
                         u16* __restrict__ x, int n){
    int i = blockIdx.x * blockDim.x + threadIdx.x;
    if (i >= n * 16) return;
    int node = i >> 4, f = i & 15;
    int a = atoms[node];
    float4 v = ((const float4*)emb)[a * 16 + f];
    ushort4 o = { f2bf(v.x), f2bf(v.y), f2bf(v.z), f2bf(v.w) };
    ((ushort4*)x)[i] = o;
}

// ---------------- EW[dh][eid][64] = edge_emb[eid] @ We[dh] ----------------
__global__ void k_ew(const float* __restrict__ edge_emb, const float* __restrict__ We,
                     float* __restrict__ EW){
    int t = blockIdx.x * blockDim.x + threadIdx.x;
    if (t >= 2 * 4 * 3 * 64) return;
    int j = t & 63, r = t >> 6;
    int eid = r % 3, dh = r / 3;
    float s = 0.f;
    for (int c = 0; c < 12; ++c)
        s += edge_emb[eid * 12 + c] * We[(dh * 12 + c) * 64 + j];
    EW[(dh * 3 + eid) * 64 + j] = s;
}

// ---------------- CSR build ----------------
__global__ void k_count(const int* __restrict__ ei, u32* cnt_t, u32* cnt_s, int E){
    int e = blockIdx.x * blockDim.x + threadIdx.x;
    if (e >= E) return;
    atomicAdd(&cnt_t[ei[E + e]], 1u);
    atomicAdd(&cnt_s[ei[e]], 1u);
}

// Hierarchical scan: 1024 elems/block (4/thread), ONE packed u64 atomic per block.
__global__ __launch_bounds__(256) void k_scan(
    const u32* __restrict__ cnt_t, const u32* __restrict__ cnt_s,
    u32* __restrict__ start_t, u32* __restrict__ start_s,
    u64* __restrict__ totals, int n)
{
    __shared__ u32 wsum_t[4], wsum_s[4];
    __shared__ u32 base_t, base_s;
    const int t0 = blockIdx.x * 1024 + threadIdx.x * 4;
    u32 ct[4], cs[4];
    #pragma unroll
    for (int j = 0; j < 4; ++j){
        int idx = t0 + j;
        ct[j] = (idx < n) ? cnt_t[idx] : 0u;
        cs[j] = (idx < n) ? cnt_s[idx] : 0u;
    }
    u32 tsum_t = ct[0] + ct[1] + ct[2] + ct[3];
    u32 tsum_s = cs[0] + cs[1] + cs[2] + cs[3];
    const int lane = threadIdx.x & 63, wv = threadIdx.x >> 6;
    u32 it = tsum_t, is = tsum_s;
    for (int d = 1; d < 64; d <<= 1){
        u32 a = __shfl_up(it, d);
        u32 b = __shfl_up(is, d);
        if (lane >= d){ it += a; is += b; }
    }
    if (lane == 63){ wsum_t[wv] = it; wsum_s[wv] = is; }
    __syncthreads();
    if (threadIdx.x == 0){
        u32 a0 = wsum_t[0], a1 = wsum_t[1], a2 = wsum_t[2], a3 = wsum_t[3];
        u32 b0 = wsum_s[0], b1 = wsum_s[1], b2 = wsum_s[2], b3 = wsum_s[3];
        u64 old = atomicAdd(totals, ((u64)(b0 + b1 + b2 + b3) << 32) | (u64)(a0 + a1 + a2 + a3));
        base_t = (u32)(old & 0xFFFFFFFFull);
        base_s = (u32)(old >> 32);
        wsum_t[0] = 0; wsum_t[1] = a0; wsum_t[2] = a0 + a1; wsum_t[3] = a0 + a1 + a2;
        wsum_s[0] = 0; wsum_s[1] = b0; wsum_s[2] = b0 + b1; wsum_s[3] = b0 + b1 + b2;
    }
    __syncthreads();
    u32 ex_t = base_t + wsum_t[wv] + (it - tsum_t);
    u32 ex_s = base_s + wsum_s[wv] + (is - tsum_s);
    #pragma unroll
    for (int j = 0; j < 4; ++j){
        int idx = t0 + j;
        if (idx < n){
            start_t[idx] = ex_t; start_s[idx] = ex_s;
            ex_t += ct[j]; ex_s += cs[j];
        }
    }
}

__global__ void k_fill(const int* __restrict__ ei, const int* __restrict__ eids,
                       const u32* __restrict__ start_t, const u32* __restrict__ start_s,
                       u32* cur_t, u32* cur_s, int* adj_t, int* adj_s, int E){
    int e = blockIdx.x * blockDim.x + threadIdx.x;
    if (e >= E) return;
    int s = ei[e], t = ei[E + e], id = eids[e];
    u32 p = atomicAdd(&cur_t[t], 1u);
    adj_t[start_t[t] + p] = s | (id << 20);
    u32 p2 = atomicAdd(&cur_s[s], 1u);
    adj_s[start_s[s] + p2] = t | (id << 20);
}

// ---------------- node GEMM via MFMA: q,k,v = x @ {Wq,Wk,Wv} + b ----
// Parity-rotated staging writes: threads with odd kk write c^2 order so lane
// pairs (kk,kk^1) never hit the same 4B LDS word in one instruction.
__global__ __launch_bounds__(256) void k_gemm3(
    const u16* __restrict__ x,
    const float* __restrict__ Wq, const float* __restrict__ bq,
    const float* __restrict__ Wk, const float* __restrict__ bk,
    const float* __restrict__ Wv, const float* __restrict__ bv,
    int dh,
    u16* __restrict__ q, u16* __restrict__ k, u16* __restrict__ v, int n)
{
    __shared__ __align__(16) u16 Wt[3][64][64];   // [mat][n][k] bf16, swizzled, 24 KB
    __shared__ __align__(16) u16 Xh[64][64];      // x tile, swizzled, 8 KB
    const int tid = threadIdx.x;
    const int row0 = blockIdx.x * 64;

    const float* wsrc[3] = { Wq + dh * 4096, Wk + dh * 4096, Wv + dh * 4096 };
    for (int m = 0; m < 3; ++m){
        for (int i = tid; i < 1024; i += 256){    // 64 k-rows x 16 float4
            int kk = i >> 4, n4 = (i & 15) * 4;
            float4 w = ((const float4*)(wsrc[m] + (size_t)kk * 64))[i & 15];
            float wf[4] = { w.x, w.y, w.z, w.w };
            int odd = kk & 1;
            #pragma unroll
            for (int c = 0; c < 4; ++c){
                int ce = odd ? (c ^ 2) : c;       // parity rotation (static extracts)
                float val = odd ? wf[c ^ 2] : wf[c];
                int nn = n4 + ce;
                int ps = (kk >> 3) ^ (nn & 7);
                Wt[m][nn][ps * 8 + (kk & 7)] = f2bf(val);
            }
        }
    }
    for (int i = tid; i < 512; i += 256){         // 64 rows x 8 slots (16B each)
        int r = i >> 3, f = i & 7;
        int gr = row0 + r;
        short8v val = {0,0,0,0,0,0,0,0};
        if (gr < n) val = *(const short8v*)&x[(size_t)gr * 64 + f * 8];
        int ps = f ^ (r & 7);
        *(short8v*)&Xh[r][ps * 8] = val;
    }
    __syncthreads();

    const int wv = tid >> 6, l = tid & 63;
    const int lr = l & 15, lk = l >> 4;
    short8v ah[2];
    #pragma unroll
    for (int ks = 0; ks < 2; ++ks){
        int r = wv * 16 + lr;
        int ps = (lk + 4 * ks) ^ (r & 7);
        ah[ks] = *(const short8v*)&Xh[r][ps * 8];
    }
    const float* bsrc[3] = { bq + dh * 64, bk + dh * 64, bv + dh * 64 };
    u16* outs[3] = { q, k, v };
    for (int m = 0; m < 3; ++m){
        #pragma unroll
        for (int ct = 0; ct < 4; ++ct){
            int col = ct * 16 + lr;
            int s0 = (lk + 0) ^ (col & 7);
            int s1 = (lk + 4) ^ (col & 7);
            short8v b0 = *(const short8v*)&Wt[m][col][s0 * 8];
            short8v b1 = *(const short8v*)&Wt[m][col][s1 * 8];
            float bb = bsrc[m][col];
            f32x4 acc = { bb, bb, bb, bb };
            acc = __builtin_amdgcn_mfma_f32_16x16x32_bf16(ah[0], b0, acc, 0, 0, 0);
            acc = __builtin_amdgcn_mfma_f32_16x16x32_bf16(ah[1], b1, acc, 0, 0, 0);
            int grb = row0 + wv * 16 + lk * 4;    // D: row=(l>>4)*4+j, col=l&15
            u16* o = outs[m];
            #pragma unroll
            for (int j = 0; j < 4; ++j)
                if (grb + j < n) o[(size_t)(grb + j) * 64 + col] = f2bf(acc[j]);
        }
    }
}

// ---------------- node-parallel attention (16 lanes/node), WRITE-ONLY output ----------------
__global__ __launch_bounds__(256) void k_attn(
    const u16* __restrict__ q, const u16* __restrict__ k, const u16* __restrict__ v,
    const int* __restrict__ adj, const u32* __restrict__ start, const u32* __restrict__ cnt,
    const float* __restrict__ EW, u16* __restrict__ outd, int n)
{
    int tid = blockIdx.x * blockDim.x + threadIdx.x;
    int node = tid >> 4;
    int l = tid & 15;
    if (node >= n) return;
    int st = (int)start[node];
    int c  = (int)cnt[node];
    ushort4 qu = ((const ushort4*)q)[node * 16 + l];
    float qx = bf2f(qu.x), qy = bf2f(qu.y), qz = bf2f(qu.z), qw = bf2f(qu.w);
    float4 acc = {0.f, 0.f, 0.f, 0.f};
    float s = 0.f;
    for (int i = 0; i < c; ++i){
        int a = adj[st + i];
        int srcn = a & 0xFFFFF;
        int eid  = ((u32)a) >> 20;
        float4 ew = ((const float4*)EW)[eid * 16 + l];
        ushort4 ku = ((const ushort4*)k)[srcn * 16 + l];
        float kx = bf2f(ku.x) + ew.x, ky = bf2f(ku.y) + ew.y;
        float kz = bf2f(ku.z) + ew.z, kw = bf2f(ku.w) + ew.w;
        float d = qx * kx + qy * ky + qz * kz + qw * kw;
        d += __shfl_xor(d, 1); d += __shfl_xor(d, 2);
        d += __shfl_xor(d, 4); d += __shfl_xor(d, 8);
        float ex = expf(d * SCALE);
        ushort4 vu = ((const ushort4*)v)[srcn * 16 + l];
        acc.x += ex * (bf2f(vu.x) + ew.x);
        acc.y += ex * (bf2f(vu.y) + ew.y);
        acc.z += ex * (bf2f(vu.z) + ew.z);
        acc.w += ex * (bf2f(vu.w) + ew.w);
        s += ex;
    }
    float inv = 1.0f / (s + 1e-16f);
    ushort4 no = { f2bf(acc.x * inv), f2bf(acc.y * inv),
                   f2bf(acc.z * inv), f2bf(acc.w * inv) };
    ((ushort4*)outd)[node * 16 + l] = no;
}

// ---------------- fused aggr: skip = x@Ws+bs (both dirs) via MFMA,
// h = concat(a0+skip0, a1+skip1) @ A + b, x' = gelu(h). LDS aliased: 40 KB.
__global__ __launch_bounds__(256) void k_aggr(
    const u16* __restrict__ a0, const u16* __restrict__ a1, const u16* __restrict__ xin,
    const float* __restrict__ Ws, const float* __restrict__ bs, int hop,
    const float* __restrict__ A, const float* __restrict__ b,
    u16* __restrict__ xout, float* __restrict__ out_f, int write_out, int n)
{
    __shared__ __align__(16) u16 lds[20480];            // 40 KB
    u16 (*Wt)[128] = (u16(*)[128])lds;                  // [64][128] A^T, swizzled, 16 KB
    u16 (*Xt)[64]  = (u16(*)[64])(lds + 8192);          // [64][64] x tile, 8 KB
    u16 (*Wst0)[64]= (u16(*)[64])(lds + 8192 + 4096);   // Ws^T dir0, 8 KB
    u16 (*Wst1)[64]= (u16(*)[64])(lds + 8192 + 8192);   // Ws^T dir1, 8 KB
    u16 (*Ah)[128] = (u16(*)[128])(lds + 8192);         // phase-3 alias over Xt/Ws*, 16 KB
    const int tid = threadIdx.x;
    const int row0 = blockIdx.x * 64;

    // ---- stage A^T: A[k][n] (128x64) -> Wt[n][k], swizzled, parity-rotated ----
    for (int i = tid; i < 2048; i += 256){
        int kk = i >> 4, n4 = (i & 15) * 4;
        float4 w = ((const float4*)(A + (size_t)kk * 64))[i & 15];
        float wf[4] = { w.x, w.y, w.z, w.w };
        int odd = kk & 1;
        #pragma unroll
        for (int c = 0; c < 4; ++c){
            int ce = odd ? (c ^ 2) : c;
            float val = odd ? wf[c ^ 2] : wf[c];
            int nn = n4 + ce;
            int ps = (kk >> 3) ^ (nn & 7);
            Wt[nn][ps * 8 + (kk & 7)] = f2bf(val);
        }
    }
    // ---- stage x tile (full-slot writes, conflict-free) ----
    for (int i = tid; i < 512; i += 256){
        int r = i >> 3, f = i & 7;
        int gr = row0 + r;
        short8v val = {0,0,0,0,0,0,0,0};
        if (gr < n) val = *(const short8v*)&xin[(size_t)gr * 64 + f * 8];
        int ps = f ^ (r & 7);
        *(short8v*)&Xt[r][ps * 8] = val;
    }
    // ---- stage Ws^T both dirs, parity-rotated ----
    const float* ws0 = Ws + (size_t)hop * 4096;
    const float* ws1 = Ws + (size_t)(4 + hop) * 4096;
    for (int i = tid; i < 1024; i += 256){
        int kk = i >> 4, n4 = (i & 15) * 4;
        float4 w0 = ((const float4*)(ws0 + (size_t)kk * 64))[i & 15];
        float4 w1 = ((const float4*)(ws1 + (size_t)kk * 64))[i & 15];
        float f0[4] = { w0.x, w0.y, w0.z, w0.w };
        float f1[4] = { w1.x, w1.y, w1.z, w1.w };
        int odd = kk & 1;
        #pragma unroll
        for (int c = 0; c < 4; ++c){
            int ce = odd ? (c ^ 2) : c;
            float v0 = odd ? f0[c ^ 2] : f0[c];
            float v1 = odd ? f1[c ^ 2] : f1[c];
            int nn = n4 + ce;
            int ps = (kk >> 3) ^ (nn & 7);
            Wst0[nn][ps * 8 + (kk & 7)] = f2bf(v0);
            Wst1[nn][ps * 8 + (kk & 7)] = f2bf(v1);
        }
    }
    __syncthreads();

    const int wv = tid >> 6, l = tid & 63;
    const int lr = l & 15, lk = l >> 4;
    // ---- phase 2: skip GEMM (both dirs) + add attn result ----
    short8v xf[2];
    #pragma unroll
    for (int ks = 0; ks < 2; ++ks){
        int r = wv * 16 + lr;
        int ps = (lk + 4 * ks) ^ (r & 7);
        xf[ks] = *(const short8v*)&Xt[r][ps * 8];
    }
    f32x4 S[2][4];
    const u16* asrc[2] = { a0, a1 };
    const int grb = row0 + wv * 16 + lk * 4;
    #pragma unroll
    for (int d = 0; d < 2; ++d){
        const float* bsd = bs + (size_t)(d * 4 + hop) * 64;
        u16 (*Wst)[64] = d ? Wst1 : Wst0;
        #pragma unroll
        for (int ct = 0; ct < 4; ++ct){
            int col = ct * 16 + lr;
            int s0 = (lk + 0) ^ (col & 7);
            int s1 = (lk + 4) ^ (col & 7);
            short8v b0 = *(const short8v*)&Wst[col][s0 * 8];
            short8v b1 = *(const short8v*)&Wst[col][s1 * 8];
            float bb = bsd[col];
            f32x4 acc = { bb, bb, bb, bb };
            acc = __builtin_amdgcn_mfma_f32_16x16x32_bf16(xf[0], b0, acc, 0, 0, 0);
            acc = __builtin_amdgcn_mfma_f32_16x16x32_bf16(xf[1], b1, acc, 0, 0, 0);
            #pragma unroll
            for (int j = 0; j < 4; ++j)
                if (grb + j < n) acc[j] += bf2f(asrc[d][(size_t)(grb + j) * 64 + col]);
            S[d][ct] = acc;
        }
    }
    __syncthreads();   // everyone done reading Xt/Ws* before Ah overwrites them
    // ---- phase 3: write concat rows into Ah, parity-rotated j order ----
    const int lodd = lr & 1;
    #pragma unroll
    for (int d = 0; d < 2; ++d){
        #pragma unroll
        for (int ct = 0; ct < 4; ++ct){
            int col = ct * 16 + lr;
            int kk = d * 64 + col;
            #pragma unroll
            for (int t = 0; t < 4; ++t){
                float val = lodd ? S[d][ct][t ^ 2] : S[d][ct][t];
                int j = lodd ? (t ^ 2) : t;
                int r = wv * 16 + lk * 4 + j;
                int ps = (kk >> 3) ^ (r & 7);
                Ah[r][ps * 8 + (kk & 7)] = f2bf(val);
            }
        }
    }
    __syncthreads();
    // ---- phase 4: h = Ah @ A + b, gelu, store ----
    short8v ah[4];
    #pragma unroll
    for (int ks = 0; ks < 4; ++ks){
        int r = wv * 16 + lr;
        int ps = (lk + 4 * ks) ^ (r & 7);
        ah[ks] = *(const short8v*)&Ah[r][ps * 8];
    }
    #pragma unroll
    for (int ct = 0; ct < 4; ++ct){
        int col = ct * 16 + lr;
        float bb = b[col];
        f32x4 acc = { bb, bb, bb, bb };
        #pragma unroll
        for (int ks = 0; ks < 4; ++ks){
            int ps = (lk + 4 * ks) ^ (col & 7);
            short8v bf = *(const short8v*)&Wt[col][ps * 8];
            acc = __builtin_amdgcn_mfma_f32_16x16x32_bf16(ah[ks], bf, acc, 0, 0, 0);
        }
        #pragma unroll
        for (int j = 0; j < 4; ++j){
            if (grb + j >= n) continue;
            float h = acc[j];
            float g = 0.5f * h * (1.0f + erff(h * 0.70710678118654752f));
            xout[(size_t)(grb + j) * 64 + col] = f2bf(g);
            if (write_out) out_f[(size_t)(grb + j) * 64 + col] = g;
        }
    }
}

extern "C" void kernel_launch(void* const* d_in, const int* in_sizes, int n_in,
                              void* d_out, int out_size, void* d_ws, size_t ws_size,
                              hipStream_t stream)
{
    const int* atoms      = (const int*)d_in[0];
    const int* ei         = (const int*)d_in[1];
    const int* eids       = (const int*)d_in[2];
    const float* atom_emb = (const float*)d_in[3];
    const float* edge_emb = (const float*)d_in[4];
    const float* Wq = (const float*)d_in[5];  const float* bq = (const float*)d_in[6];
    const float* Wk = (const float*)d_in[7];  const float* bk = (const float*)d_in[8];
    const float* Wv = (const float*)d_in[9];  const float* bv = (const float*)d_in[10];
    const float* We = (const float*)d_in[11];
    const float* Ws = (const float*)d_in[12]; const float* bs = (const float*)d_in[13];
    const float* aggr_W = (const float*)d_in[14];
    const float* aggr_b = (const float*)d_in[15];

    const int N = in_sizes[0];
    const int E = in_sizes[1] / 2;

    char* p = (char*)d_ws;
    auto alloc = [&](size_t bytes){
        void* r = (void*)p;
        p += (bytes + 255) & ~(size_t)255;
        return r;
    };
    u16*   x   = (u16*)  alloc((size_t)N * 64 * 2);
    u16*   qb  = (u16*)  alloc((size_t)N * 64 * 2);
    u16*   kb  = (u16*)  alloc((size_t)N * 64 * 2);
    u16*   vb  = (u16*)  alloc((size_t)N * 64 * 2);
    u16*   o0  = (u16*)  alloc((size_t)N * 64 * 2);
    u16*   o1  = (u16*)  alloc((size_t)N * 64 * 2);
    float* EWt = (float*)alloc(2 * 4 * 3 * 64 * 4);
    int* adj_t = (int*)alloc((size_t)E * 4);
    int* adj_s = (int*)alloc((size_t)E * 4);
    u32* start_t = (u32*)alloc((size_t)N * 4);
    u32* start_s = (u32*)alloc((size_t)N * 4);
    u32* zb = (u32*)alloc(((size_t)4 * N + 2) * 4);   // cnt_t cnt_s cur_t cur_s totals(u64)
    u32* cnt_t = zb;
    u32* cnt_s = zb + N;
    u32* cur_t = zb + 2 * (size_t)N;
    u32* cur_s = zb + 3 * (size_t)N;
    u64* totals = (u64*)(zb + 4 * (size_t)N);   // 4N u32s = 8-byte aligned

    hipMemsetAsync(zb, 0, ((size_t)4 * N + 2) * 4, stream);

    k_gather<<<(N * 16 + 255) / 256, 256, 0, stream>>>(atoms, atom_emb, x, N);
    k_ew<<<6, 256, 0, stream>>>(edge_emb, We, EWt);
    k_count<<<(E + 255) / 256, 256, 0, stream>>>(ei, cnt_t, cnt_s, E);
    k_scan<<<(N + 1023) / 1024, 256, 0, stream>>>(cnt_t, cnt_s, start_t, start_s, totals, N);
    k_fill<<<(E + 255) / 256, 256, 0, stream>>>(ei, eids, start_t, start_s, cur_t, cur_s, adj_t, adj_s, E);

    const int gB = (N + 63) / 64;
    const int gA = (N * 16 + 255) / 256;
    for (int hop = 0; hop < 4; ++hop){
        int dh0 = hop;         // dir 0 (r2c)
        int dh1 = 4 + hop;     // dir 1 (c2r)
        k_gemm3<<<gB, 256, 0, stream>>>(x, Wq, bq, Wk, bk, Wv, bv, dh0, qb, kb, vb, N);
        k_attn<<<gA, 256, 0, stream>>>(qb, kb, vb, adj_t, start_t, cnt_t, EWt + dh0 * 192, o0, N);
        k_gemm3<<<gB, 256, 0, stream>>>(x, Wq, bq, Wk, bk, Wv, bv, dh1, qb, kb, vb, N);
        k_attn<<<gA, 256, 0, stream>>>(qb, kb, vb, adj_s, start_s, cnt_s, EWt + dh1 * 192, o1, N);
        k_aggr<<<gB, 256, 0, stream>>>(o0, o1, x, Ws, bs, hop, aggr_W, aggr_b,
                                       x, (float*)d_out, hop == 3 ? 1 : 0, N);
    }
}